// Round 1
// baseline (622.535 us; speedup 1.0000x reference)
//
#include <hip/hip_runtime.h>
#include <hip/hip_bf16.h>
#include <math.h>

// Problem constants
// x:      [4, 1024, 768]   fp32
// w_qkv:  [768, 2304]      fp32   (x @ w_qkv)
// w_out:  [768, 768]       fp32
// b_out:  [768]            fp32
// out:    [4, 1024, 768]   fp32
// HEADS=12, DH=64, SCALE=1/8

// ---------------------------------------------------------------------------
// Kernel 1: qkv = x @ w_qkv, scattered into Q/K/V in [b*h][n][d] layout
// M=4096, K=768, N=2304.  128x128 tile, 256 threads, 8x8 per thread.
// ---------------------------------------------------------------------------
__global__ __launch_bounds__(256) void qkv_gemm(const float* __restrict__ x,
                                                const float* __restrict__ w,
                                                float* __restrict__ Qb,
                                                float* __restrict__ Kb,
                                                float* __restrict__ Vb) {
    __shared__ float As[16][129];   // [k][m], padded to kill store conflicts
    __shared__ float Bs[16][128];   // [k][n]
    const int tid = threadIdx.x;
    const int tx = tid & 15;
    const int ty = tid >> 4;
    const int row0 = blockIdx.y * 128;
    const int col0 = blockIdx.x * 128;

    float acc[8][8];
#pragma unroll
    for (int i = 0; i < 8; ++i)
#pragma unroll
        for (int j = 0; j < 8; ++j) acc[i][j] = 0.f;

    for (int k0 = 0; k0 < 768; k0 += 16) {
        // A tile: 128 rows x 16 k, transposed into As[k][m]
#pragma unroll
        for (int l = 0; l < 2; ++l) {
            int idx = tid + l * 256;
            int ar = idx >> 2;
            int ac4 = idx & 3;
            float4 v = *reinterpret_cast<const float4*>(&x[(size_t)(row0 + ar) * 768 + k0 + ac4 * 4]);
            As[ac4 * 4 + 0][ar] = v.x;
            As[ac4 * 4 + 1][ar] = v.y;
            As[ac4 * 4 + 2][ar] = v.z;
            As[ac4 * 4 + 3][ar] = v.w;
        }
        // B tile: 16 k x 128 cols
#pragma unroll
        for (int l = 0; l < 2; ++l) {
            int idx = tid + l * 256;
            int br = idx >> 5;
            int bc4 = idx & 31;
            float4 v = *reinterpret_cast<const float4*>(&w[(size_t)(k0 + br) * 2304 + col0 + bc4 * 4]);
            *reinterpret_cast<float4*>(&Bs[br][bc4 * 4]) = v;
        }
        __syncthreads();
#pragma unroll
        for (int kk = 0; kk < 16; ++kk) {
            float a_reg[8], b_reg[8];
#pragma unroll
            for (int i = 0; i < 8; ++i) a_reg[i] = As[kk][ty + 16 * i];
#pragma unroll
            for (int j = 0; j < 8; ++j) b_reg[j] = Bs[kk][tx + 16 * j];
#pragma unroll
            for (int i = 0; i < 8; ++i)
#pragma unroll
                for (int j = 0; j < 8; ++j) acc[i][j] += a_reg[i] * b_reg[j];
        }
        __syncthreads();
    }

    // scatter into head-major Q/K/V: dst[((b*12+h)*1024 + n)*64 + d]
    const int which = col0 / 768;            // 128 | 768, so uniform per block
    const int cbase = col0 - which * 768;
    float* dst = (which == 0) ? Qb : (which == 1) ? Kb : Vb;
#pragma unroll
    for (int i = 0; i < 8; ++i) {
        int r = row0 + ty + 16 * i;
        int b = r >> 10;
        int n = r & 1023;
#pragma unroll
        for (int j = 0; j < 8; ++j) {
            int cw = cbase + tx + 16 * j;
            int h = cw >> 6;
            int d = cw & 63;
            dst[(size_t)((b * 12 + h) * 1024 + n) * 64 + d] = acc[i][j];
        }
    }
}

// ---------------------------------------------------------------------------
// Kernel 2: flash attention per (q-tile, b*h).  Q tile 64x64, K/V tiles 64x64.
// 256 threads; thread (tx,ty) owns rows {ty+16i}, cols {tx+16j}, i,j in 0..3.
// ---------------------------------------------------------------------------
__global__ __launch_bounds__(256) void attn_kernel(const float* __restrict__ Qb,
                                                   const float* __restrict__ Kb,
                                                   const float* __restrict__ Vb,
                                                   float* __restrict__ attn_out) {
    __shared__ float Qs[64][68];
    __shared__ float Ks[64][68];
    __shared__ float Vs[64][68];
    __shared__ float Ss[64][68];
    __shared__ float mrow[64], lrow[64], crow[64];

    const int tid = threadIdx.x;
    const int tx = tid & 15;
    const int ty = tid >> 4;
    const int qt = blockIdx.x;   // 0..15
    const int bh = blockIdx.y;   // 0..47
    const float scale = 0.125f;

    const float* Qh = Qb + (size_t)bh * 1024 * 64;
    const float* Kh = Kb + (size_t)bh * 1024 * 64;
    const float* Vh = Vb + (size_t)bh * 1024 * 64;

    // load Q tile (64x64): 256 threads x 4 float4
#pragma unroll
    for (int l = 0; l < 4; ++l) {
        int idx = tid + l * 256;
        int r = idx >> 4;
        int c4 = idx & 15;
        float4 v = *reinterpret_cast<const float4*>(&Qh[(size_t)(qt * 64 + r) * 64 + c4 * 4]);
        *reinterpret_cast<float4*>(&Qs[r][c4 * 4]) = v;   // row stride 272B = 16B-aligned
    }
    if (tid < 64) { mrow[tid] = -1e30f; lrow[tid] = 0.f; }

    float o[4][4];
#pragma unroll
    for (int i = 0; i < 4; ++i)
#pragma unroll
        for (int j = 0; j < 4; ++j) o[i][j] = 0.f;

    for (int kt = 0; kt < 16; ++kt) {
        __syncthreads();   // prev iter done with Ks/Vs/Ss; Q visible on iter 0
#pragma unroll
        for (int l = 0; l < 4; ++l) {
            int idx = tid + l * 256;
            int r = idx >> 4;
            int c4 = idx & 15;
            float4 kv = *reinterpret_cast<const float4*>(&Kh[(size_t)(kt * 64 + r) * 64 + c4 * 4]);
            *reinterpret_cast<float4*>(&Ks[r][c4 * 4]) = kv;
            float4 vv = *reinterpret_cast<const float4*>(&Vh[(size_t)(kt * 64 + r) * 64 + c4 * 4]);
            *reinterpret_cast<float4*>(&Vs[r][c4 * 4]) = vv;
        }
        __syncthreads();

        // S = Q K^T * scale  (each thread 4x4)
        float s[4][4];
#pragma unroll
        for (int i = 0; i < 4; ++i)
#pragma unroll
            for (int j = 0; j < 4; ++j) s[i][j] = 0.f;
        for (int d = 0; d < 64; ++d) {
            float qv[4], kv[4];
#pragma unroll
            for (int i = 0; i < 4; ++i) qv[i] = Qs[ty + 16 * i][d];
#pragma unroll
            for (int j = 0; j < 4; ++j) kv[j] = Ks[tx + 16 * j][d];
#pragma unroll
            for (int i = 0; i < 4; ++i)
#pragma unroll
                for (int j = 0; j < 4; ++j) s[i][j] += qv[i] * kv[j];
        }
#pragma unroll
        for (int i = 0; i < 4; ++i)
#pragma unroll
            for (int j = 0; j < 4; ++j) Ss[ty + 16 * i][tx + 16 * j] = s[i][j] * scale;
        __syncthreads();

        // online softmax, one thread per row
        if (tid < 64) {
            int r = tid;
            float m0 = mrow[r];
            float tm = m0;
            for (int c = 0; c < 64; ++c) tm = fmaxf(tm, Ss[r][c]);
            float corr = __expf(m0 - tm);
            float ps = 0.f;
            for (int c = 0; c < 64; ++c) {
                float p = __expf(Ss[r][c] - tm);
                Ss[r][c] = p;
                ps += p;
            }
            lrow[r] = lrow[r] * corr + ps;
            mrow[r] = tm;
            crow[r] = corr;
        }
        __syncthreads();

        // O = O*corr + P @ V
        float cf[4];
#pragma unroll
        for (int i = 0; i < 4; ++i) cf[i] = crow[ty + 16 * i];
#pragma unroll
        for (int i = 0; i < 4; ++i)
#pragma unroll
            for (int j = 0; j < 4; ++j) o[i][j] *= cf[i];
        for (int kk = 0; kk < 64; ++kk) {
            float pv[4], vv[4];
#pragma unroll
            for (int i = 0; i < 4; ++i) pv[i] = Ss[ty + 16 * i][kk];
#pragma unroll
            for (int j = 0; j < 4; ++j) vv[j] = Vs[kk][tx + 16 * j];
#pragma unroll
            for (int i = 0; i < 4; ++i)
#pragma unroll
                for (int j = 0; j < 4; ++j) o[i][j] += pv[i] * vv[j];
        }
    }
    __syncthreads();

    // normalize + write to [b, n, h*64+d]
    const int b = bh / 12;
    const int h = bh % 12;
#pragma unroll
    for (int i = 0; i < 4; ++i) {
        int grow = qt * 64 + ty + 16 * i;
        float inv = 1.0f / lrow[ty + 16 * i];
#pragma unroll
        for (int j = 0; j < 4; ++j) {
            attn_out[(size_t)(b * 1024 + grow) * 768 + h * 64 + tx + 16 * j] = o[i][j] * inv;
        }
    }
}

// ---------------------------------------------------------------------------
// Kernel 3: out = attn @ w_out + b_out.  M=4096, K=768, N=768.
// ---------------------------------------------------------------------------
__global__ __launch_bounds__(256) void out_gemm(const float* __restrict__ a,
                                                const float* __restrict__ w,
                                                const float* __restrict__ bias,
                                                float* __restrict__ out) {
    __shared__ float As[16][129];
    __shared__ float Bs[16][128];
    const int tid = threadIdx.x;
    const int tx = tid & 15;
    const int ty = tid >> 4;
    const int row0 = blockIdx.y * 128;
    const int col0 = blockIdx.x * 128;

    float acc[8][8];
#pragma unroll
    for (int i = 0; i < 8; ++i)
#pragma unroll
        for (int j = 0; j < 8; ++j) acc[i][j] = 0.f;

    for (int k0 = 0; k0 < 768; k0 += 16) {
#pragma unroll
        for (int l = 0; l < 2; ++l) {
            int idx = tid + l * 256;
            int ar = idx >> 2;
            int ac4 = idx & 3;
            float4 v = *reinterpret_cast<const float4*>(&a[(size_t)(row0 + ar) * 768 + k0 + ac4 * 4]);
            As[ac4 * 4 + 0][ar] = v.x;
            As[ac4 * 4 + 1][ar] = v.y;
            As[ac4 * 4 + 2][ar] = v.z;
            As[ac4 * 4 + 3][ar] = v.w;
        }
#pragma unroll
        for (int l = 0; l < 2; ++l) {
            int idx = tid + l * 256;
            int br = idx >> 5;
            int bc4 = idx & 31;
            float4 v = *reinterpret_cast<const float4*>(&w[(size_t)(k0 + br) * 768 + col0 + bc4 * 4]);
            *reinterpret_cast<float4*>(&Bs[br][bc4 * 4]) = v;
        }
        __syncthreads();
#pragma unroll
        for (int kk = 0; kk < 16; ++kk) {
            float a_reg[8], b_reg[8];
#pragma unroll
            for (int i = 0; i < 8; ++i) a_reg[i] = As[kk][ty + 16 * i];
#pragma unroll
            for (int j = 0; j < 8; ++j) b_reg[j] = Bs[kk][tx + 16 * j];
#pragma unroll
            for (int i = 0; i < 8; ++i)
#pragma unroll
                for (int j = 0; j < 8; ++j) acc[i][j] += a_reg[i] * b_reg[j];
        }
        __syncthreads();
    }
#pragma unroll
    for (int i = 0; i < 8; ++i) {
        int r = row0 + ty + 16 * i;
#pragma unroll
        for (int j = 0; j < 8; ++j) {
            int c = col0 + tx + 16 * j;
            out[(size_t)r * 768 + c] = acc[i][j] + bias[c];
        }
    }
}

// ---------------------------------------------------------------------------
extern "C" void kernel_launch(void* const* d_in, const int* in_sizes, int n_in,
                              void* d_out, int out_size, void* d_ws, size_t ws_size,
                              hipStream_t stream) {
    const float* x = (const float*)d_in[0];       // [4,1024,768]
    const float* w_qkv = (const float*)d_in[1];   // [768,2304]
    const float* w_out = (const float*)d_in[2];   // [768,768]
    const float* b_out = (const float*)d_in[3];   // [768]
    float* out = (float*)d_out;

    float* ws = (float*)d_ws;
    const size_t per = (size_t)4 * 12 * 1024 * 64;   // 3,145,728 elements
    float* Qb = ws;
    float* Kb = ws + per;
    float* Vb = ws + 2 * per;
    float* attn = ws + 3 * per;

    qkv_gemm<<<dim3(18, 32), 256, 0, stream>>>(x, w_qkv, Qb, Kb, Vb);
    attn_kernel<<<dim3(16, 48), 256, 0, stream>>>(Qb, Kb, Vb, attn);
    out_gemm<<<dim3(6, 32), 256, 0, stream>>>(attn, w_out, b_out, out);
}

// Round 2
// 129.672 us; speedup vs baseline: 4.8009x; 4.8009x over previous
//
#include <hip/hip_runtime.h>
#include <math.h>

// x:      [4,1024,768] fp32 -> bf16
// w_qkv:  [768,2304]   fp32 -> bf16 transposed [2304,768]
// w_out:  [768,768]    fp32 -> bf16 transposed [768,768]
// b_out:  [768]        fp32
// out:    [4,1024,768] fp32
// HEADS=12, DH=64, SCALE=0.125 (folded into Q, exact power of 2)

typedef __attribute__((ext_vector_type(8))) __bf16 bf16x8;
typedef __attribute__((ext_vector_type(4))) float f32x4;
typedef unsigned short u16;

__device__ __forceinline__ u16 f2bf(float f) {
    union { float f; unsigned u; } v; v.f = f;
    unsigned r = v.u + 0x7FFF + ((v.u >> 16) & 1);   // RNE
    return (u16)(r >> 16);
}

// ---------------------------------------------------------------------------
// fp32 -> bf16 elementwise (vectorized: float4 in, 4x bf16 out)
// ---------------------------------------------------------------------------
__global__ void convert_x(const float* __restrict__ in, u16* __restrict__ out, int n4) {
    int i = blockIdx.x * blockDim.x + threadIdx.x;
    if (i < n4) {
        float4 v = reinterpret_cast<const float4*>(in)[i];
        union { u16 s[4]; int2 p; } o;
        o.s[0] = f2bf(v.x); o.s[1] = f2bf(v.y); o.s[2] = f2bf(v.z); o.s[3] = f2bf(v.w);
        reinterpret_cast<int2*>(out)[i] = o.p;
    }
}

// ---------------------------------------------------------------------------
// fp32 [R][C] -> bf16 [C][R], LDS-tiled 32x32
// ---------------------------------------------------------------------------
__global__ __launch_bounds__(256) void transpose_convert(const float* __restrict__ in,
                                                         u16* __restrict__ out,
                                                         int R, int C) {
    __shared__ float T[32][33];
    const int tx = threadIdx.x & 31;
    const int ty = threadIdx.x >> 5;         // 0..7
    const int c0 = blockIdx.x * 32;
    const int r0 = blockIdx.y * 32;
#pragma unroll
    for (int p = 0; p < 4; ++p) {
        int ry = ty + p * 8;
        T[ry][tx] = in[(size_t)(r0 + ry) * C + c0 + tx];
    }
    __syncthreads();
#pragma unroll
    for (int p = 0; p < 4; ++p) {
        int cy = ty + p * 8;
        out[(size_t)(c0 + cy) * R + r0 + tx] = f2bf(T[tx][cy]);
    }
}

// ---------------------------------------------------------------------------
// GEMM1: qkv = x_bf16 @ w_qkv (via wqkvT), scatter to Q(scaled)/K [bh][n][d]
// and V transposed [bh][d][n].  M=4096 K=768 N=2304.  128x128 tile, 4 waves.
// ---------------------------------------------------------------------------
__global__ __launch_bounds__(256) void gemm_qkv(const u16* __restrict__ A,   // [4096][768]
                                                const u16* __restrict__ BT,  // [2304][768]
                                                u16* __restrict__ Qb,
                                                u16* __restrict__ Kb,
                                                u16* __restrict__ Vt) {
    __shared__ u16 As[128][40];   // pad 32->40: 80B rows, 2-way (free) bank access
    __shared__ u16 Bs[128][40];
    const int tid = threadIdx.x;
    const int lane = tid & 63;
    const int w = tid >> 6;
    const int wm = w >> 1, wn = w & 1;
    const int lr = lane & 15;
    const int lk = lane >> 4;
    const int row0 = blockIdx.y * 128;
    const int col0 = blockIdx.x * 128;

    f32x4 acc[4][4];
#pragma unroll
    for (int mi = 0; mi < 4; ++mi)
#pragma unroll
        for (int nj = 0; nj < 4; ++nj) acc[mi][nj] = (f32x4){0.f, 0.f, 0.f, 0.f};

    for (int k0 = 0; k0 < 768; k0 += 32) {
#pragma unroll
        for (int l = 0; l < 2; ++l) {
            int idx = tid + l * 256;          // 0..511
            int r = idx >> 2;                 // 0..127
            int cg = idx & 3;                 // 16B group
            *reinterpret_cast<int4*>(&As[r][cg * 8]) =
                *reinterpret_cast<const int4*>(&A[(size_t)(row0 + r) * 768 + k0 + cg * 8]);
            *reinterpret_cast<int4*>(&Bs[r][cg * 8]) =
                *reinterpret_cast<const int4*>(&BT[(size_t)(col0 + r) * 768 + k0 + cg * 8]);
        }
        __syncthreads();
        bf16x8 af[4], bfr[4];
#pragma unroll
        for (int mi = 0; mi < 4; ++mi)
            af[mi] = *reinterpret_cast<const bf16x8*>(&As[wm * 64 + mi * 16 + lr][lk * 8]);
#pragma unroll
        for (int nj = 0; nj < 4; ++nj)
            bfr[nj] = *reinterpret_cast<const bf16x8*>(&Bs[wn * 64 + nj * 16 + lr][lk * 8]);
#pragma unroll
        for (int mi = 0; mi < 4; ++mi)
#pragma unroll
            for (int nj = 0; nj < 4; ++nj)
                acc[mi][nj] = __builtin_amdgcn_mfma_f32_16x16x32_bf16(af[mi], bfr[nj], acc[mi][nj], 0, 0, 0);
        __syncthreads();
    }

    const int which = col0 / 768;       // 0:Q 1:K 2:V (768%128==0, uniform per block)
    const int cb = col0 - which * 768;
#pragma unroll
    for (int mi = 0; mi < 4; ++mi) {
#pragma unroll
        for (int i = 0; i < 4; ++i) {
            int r = row0 + wm * 64 + mi * 16 + lk * 4 + i;
            int b = r >> 10, n = r & 1023;
#pragma unroll
            for (int nj = 0; nj < 4; ++nj) {
                int cw = cb + wn * 64 + nj * 16 + lr;
                int h = cw >> 6, d = cw & 63;
                int bh = b * 12 + h;
                float val = acc[mi][nj][i];
                if (which == 0)      Qb[((size_t)bh * 1024 + n) * 64 + d] = f2bf(val * 0.125f);
                else if (which == 1) Kb[((size_t)bh * 1024 + n) * 64 + d] = f2bf(val);
                else                 Vt[((size_t)bh * 64 + d) * 1024 + n] = f2bf(val);
            }
        }
    }
}

// ---------------------------------------------------------------------------
// Flash attention, MFMA.  Block = (qtile of 64 rows) x (bh).  4 waves,
// wave w owns q-rows [w*16, w*16+16).  K tiles of 64 keys.
// Q pre-scaled by 0.125.  V stored [bh][d][n] (transposed).
// ---------------------------------------------------------------------------
__global__ __launch_bounds__(256) void attn_mfma(const u16* __restrict__ Qb,
                                                 const u16* __restrict__ Kb,
                                                 const u16* __restrict__ Vt,
                                                 u16* __restrict__ attn_out) {
    __shared__ u16 Ks[64][72];   // [key][d]   pad 64->72: 144B rows
    __shared__ u16 Vs[64][72];   // [d][key]
    __shared__ u16 Ps[64][72];   // [qrow][key] wave-private row bands
    const int tid = threadIdx.x;
    const int lane = tid & 63;
    const int w = tid >> 6;
    const int lr = lane & 15;
    const int lk = lane >> 4;
    const int qt = blockIdx.x;   // 0..15
    const int bh = blockIdx.y;   // 0..47

    const u16* Qh = Qb + (size_t)bh * 1024 * 64;
    const u16* Kh = Kb + (size_t)bh * 1024 * 64;
    const u16* Vh = Vt + (size_t)bh * 64 * 1024;

    // Q fragments in registers for the whole kernel (A-operand, 16 q-rows/wave)
    bf16x8 qf[2];
#pragma unroll
    for (int ks = 0; ks < 2; ++ks)
        qf[ks] = *reinterpret_cast<const bf16x8*>(&Qh[(size_t)(qt * 64 + w * 16 + lr) * 64 + ks * 32 + lk * 8]);

    f32x4 po[4];                 // O acc: row = lk*4+i, d = dt*16+lr
#pragma unroll
    for (int dt = 0; dt < 4; ++dt) po[dt] = (f32x4){0.f, 0.f, 0.f, 0.f};
    float m_i[4], l_i[4];
#pragma unroll
    for (int i = 0; i < 4; ++i) { m_i[i] = -1e30f; l_i[i] = 0.f; }

    for (int kt = 0; kt < 16; ++kt) {
        __syncthreads();                       // all waves done reading Ks/Vs
#pragma unroll
        for (int l = 0; l < 2; ++l) {
            int idx = tid + l * 256;           // 0..511
            int r = idx >> 3, g = idx & 7;
            *reinterpret_cast<int4*>(&Ks[r][g * 8]) =
                *reinterpret_cast<const int4*>(&Kh[(size_t)(kt * 64 + r) * 64 + g * 8]);
            *reinterpret_cast<int4*>(&Vs[r][g * 8]) =
                *reinterpret_cast<const int4*>(&Vh[(size_t)r * 1024 + kt * 64 + g * 8]);
        }
        __syncthreads();

        // S = Q K^T  (pre-scaled).  s[ct]: rows lk*4+i, cols ct*16+lr
        f32x4 s[4];
#pragma unroll
        for (int ct = 0; ct < 4; ++ct) s[ct] = (f32x4){0.f, 0.f, 0.f, 0.f};
#pragma unroll
        for (int ct = 0; ct < 4; ++ct)
#pragma unroll
            for (int ks = 0; ks < 2; ++ks) {
                bf16x8 kb = *reinterpret_cast<const bf16x8*>(&Ks[ct * 16 + lr][ks * 32 + lk * 8]);
                s[ct] = __builtin_amdgcn_mfma_f32_16x16x32_bf16(qf[ks], kb, s[ct], 0, 0, 0);
            }

        // online softmax, wave-parallel (reduce across the 16 lanes of lr)
        float corr[4];
#pragma unroll
        for (int i = 0; i < 4; ++i) {
            float tm = fmaxf(fmaxf(s[0][i], s[1][i]), fmaxf(s[2][i], s[3][i]));
            tm = fmaxf(tm, __shfl_xor(tm, 1));
            tm = fmaxf(tm, __shfl_xor(tm, 2));
            tm = fmaxf(tm, __shfl_xor(tm, 4));
            tm = fmaxf(tm, __shfl_xor(tm, 8));
            float mn = fmaxf(m_i[i], tm);
            corr[i] = __expf(m_i[i] - mn);
            m_i[i] = mn;
            float ps = 0.f;
#pragma unroll
            for (int ct = 0; ct < 4; ++ct) {
                float p = __expf(s[ct][i] - mn);
                s[ct][i] = p;
                ps += p;
            }
            ps += __shfl_xor(ps, 1);
            ps += __shfl_xor(ps, 2);
            ps += __shfl_xor(ps, 4);
            ps += __shfl_xor(ps, 8);
            l_i[i] = l_i[i] * corr[i] + ps;
        }

        // P -> LDS (wave-private rows), rescale O
#pragma unroll
        for (int ct = 0; ct < 4; ++ct)
#pragma unroll
            for (int i = 0; i < 4; ++i)
                Ps[w * 16 + lk * 4 + i][ct * 16 + lr] = f2bf(s[ct][i]);
#pragma unroll
        for (int dt = 0; dt < 4; ++dt)
#pragma unroll
            for (int i = 0; i < 4; ++i) po[dt][i] *= corr[i];

        // O += P @ V.  A=P from Ps; B=V via Vs[d][key] (contiguous reads)
#pragma unroll
        for (int ks = 0; ks < 2; ++ks) {
            bf16x8 pa = *reinterpret_cast<const bf16x8*>(&Ps[w * 16 + lr][ks * 32 + lk * 8]);
#pragma unroll
            for (int dt = 0; dt < 4; ++dt) {
                bf16x8 vb = *reinterpret_cast<const bf16x8*>(&Vs[dt * 16 + lr][ks * 32 + lk * 8]);
                po[dt] = __builtin_amdgcn_mfma_f32_16x16x32_bf16(pa, vb, po[dt], 0, 0, 0);
            }
        }
    }

    // normalize, write bf16 to [b][n][h*64+d]
    const int b = bh / 12, h = bh % 12;
#pragma unroll
    for (int i = 0; i < 4; ++i) {
        float inv = 1.0f / l_i[i];
        int n = qt * 64 + w * 16 + lk * 4 + i;
#pragma unroll
        for (int dt = 0; dt < 4; ++dt)
            attn_out[((size_t)(b * 1024 + n)) * 768 + h * 64 + dt * 16 + lr] = f2bf(po[dt][i] * inv);
    }
}

// ---------------------------------------------------------------------------
// GEMM2: out = attn_bf16 @ w_out (via woutT) + b_out.  M=4096 K=768 N=768.
// ---------------------------------------------------------------------------
__global__ __launch_bounds__(256) void gemm_out(const u16* __restrict__ A,   // [4096][768]
                                                const u16* __restrict__ BT,  // [768][768]
                                                const float* __restrict__ bias,
                                                float* __restrict__ out) {
    __shared__ u16 As[128][40];
    __shared__ u16 Bs[128][40];
    const int tid = threadIdx.x;
    const int lane = tid & 63;
    const int w = tid >> 6;
    const int wm = w >> 1, wn = w & 1;
    const int lr = lane & 15;
    const int lk = lane >> 4;
    const int row0 = blockIdx.y * 128;
    const int col0 = blockIdx.x * 128;

    f32x4 acc[4][4];
#pragma unroll
    for (int mi = 0; mi < 4; ++mi)
#pragma unroll
        for (int nj = 0; nj < 4; ++nj) acc[mi][nj] = (f32x4){0.f, 0.f, 0.f, 0.f};

    for (int k0 = 0; k0 < 768; k0 += 32) {
#pragma unroll
        for (int l = 0; l < 2; ++l) {
            int idx = tid + l * 256;
            int r = idx >> 2;
            int cg = idx & 3;
            *reinterpret_cast<int4*>(&As[r][cg * 8]) =
                *reinterpret_cast<const int4*>(&A[(size_t)(row0 + r) * 768 + k0 + cg * 8]);
            *reinterpret_cast<int4*>(&Bs[r][cg * 8]) =
                *reinterpret_cast<const int4*>(&BT[(size_t)(col0 + r) * 768 + k0 + cg * 8]);
        }
        __syncthreads();
        bf16x8 af[4], bfr[4];
#pragma unroll
        for (int mi = 0; mi < 4; ++mi)
            af[mi] = *reinterpret_cast<const bf16x8*>(&As[wm * 64 + mi * 16 + lr][lk * 8]);
#pragma unroll
        for (int nj = 0; nj < 4; ++nj)
            bfr[nj] = *reinterpret_cast<const bf16x8*>(&Bs[wn * 64 + nj * 16 + lr][lk * 8]);
#pragma unroll
        for (int mi = 0; mi < 4; ++mi)
#pragma unroll
            for (int nj = 0; nj < 4; ++nj)
                acc[mi][nj] = __builtin_amdgcn_mfma_f32_16x16x32_bf16(af[mi], bfr[nj], acc[mi][nj], 0, 0, 0);
        __syncthreads();
    }

#pragma unroll
    for (int mi = 0; mi < 4; ++mi)
#pragma unroll
        for (int i = 0; i < 4; ++i) {
            int r = row0 + wm * 64 + mi * 16 + lk * 4 + i;
#pragma unroll
            for (int nj = 0; nj < 4; ++nj) {
                int c = col0 + wn * 64 + nj * 16 + lr;
                out[(size_t)r * 768 + c] = acc[mi][nj][i] + bias[c];
            }
        }
}

// ---------------------------------------------------------------------------
extern "C" void kernel_launch(void* const* d_in, const int* in_sizes, int n_in,
                              void* d_out, int out_size, void* d_ws, size_t ws_size,
                              hipStream_t stream) {
    const float* x     = (const float*)d_in[0];   // [4,1024,768]
    const float* w_qkv = (const float*)d_in[1];   // [768,2304]
    const float* w_out = (const float*)d_in[2];   // [768,768]
    const float* b_out = (const float*)d_in[3];   // [768]
    float* out = (float*)d_out;

    u16* ws = (u16*)d_ws;
    const size_t n_x = (size_t)4096 * 768;        // 3,145,728
    u16* xb     = ws;                             // [4096][768]
    u16* wqkvT  = xb + n_x;                       // [2304][768]
    u16* woutT  = wqkvT + (size_t)2304 * 768;     // [768][768]
    u16* Qb     = woutT + (size_t)768 * 768;      // [48][1024][64]
    u16* Kb     = Qb + n_x;
    u16* Vtr    = Kb + n_x;                       // [48][64][1024]
    u16* attnb  = Vtr + n_x;                      // [4096][768]

    convert_x<<<(786432 + 255) / 256, 256, 0, stream>>>(x, xb, 786432);
    transpose_convert<<<dim3(72, 24), 256, 0, stream>>>(w_qkv, wqkvT, 768, 2304);
    transpose_convert<<<dim3(24, 24), 256, 0, stream>>>(w_out, woutT, 768, 768);
    gemm_qkv<<<dim3(18, 32), 256, 0, stream>>>(xb, wqkvT, Qb, Kb, Vtr);
    attn_mfma<<<dim3(16, 48), 256, 0, stream>>>(Qb, Kb, Vtr, attnb);
    gemm_out<<<dim3(6, 32), 256, 0, stream>>>(attnb, woutT, b_out, out);
}

// Round 4
// 129.508 us; speedup vs baseline: 4.8069x; 1.0013x over previous
//
#include <hip/hip_runtime.h>
#include <math.h>

// x:      [4,1024,768] fp32 -> bf16
// w_qkv:  [768,2304]   fp32 -> bf16 transposed [2304,768]
// w_out:  [768,768]    fp32 -> bf16 transposed [768,768]
// b_out:  [768]        fp32
// out:    [4,1024,768] fp32
// HEADS=12, DH=64.  Q pre-scaled by 0.125*log2(e) -> softmax in exp2 domain.

typedef __attribute__((ext_vector_type(8))) __bf16 bf16x8;
typedef __attribute__((ext_vector_type(4))) float f32x4;
typedef __attribute__((ext_vector_type(16))) float f32x16;
typedef unsigned short u16;
typedef unsigned int u32;

#define ZERO16 {0,0,0,0,0,0,0,0,0,0,0,0,0,0,0,0}

__device__ __forceinline__ u16 f2bf(float f) {
    union { float f; unsigned u; } v; v.f = f;
    unsigned r = v.u + 0x7FFF + ((v.u >> 16) & 1);   // RNE
    return (u16)(r >> 16);
}

__device__ __forceinline__ u32 cvtpk(float lo, float hi) {
    u32 r;
    asm("v_cvt_pk_bf16_f32 %0, %1, %2" : "=v"(r) : "v"(lo), "v"(hi));
    return r;
}
// cross-half (lane ^ 32) exchange via shfl (defined semantics, no alias hazard)
__device__ __forceinline__ float xhalf_max(float x) {
    float o = __shfl_xor(x, 32);
    return fmaxf(x, o);
}
__device__ __forceinline__ float xhalf_sum(float x) {
    float o = __shfl_xor(x, 32);
    return x + o;
}

// ---------------------------------------------------------------------------
__global__ void convert_x(const float* __restrict__ in, u16* __restrict__ out, int n4) {
    int i = blockIdx.x * blockDim.x + threadIdx.x;
    if (i < n4) {
        float4 v = reinterpret_cast<const float4*>(in)[i];
        union { u16 s[4]; int2 p; } o;
        o.s[0] = f2bf(v.x); o.s[1] = f2bf(v.y); o.s[2] = f2bf(v.z); o.s[3] = f2bf(v.w);
        reinterpret_cast<int2*>(out)[i] = o.p;
    }
}

__global__ __launch_bounds__(256) void transpose_convert(const float* __restrict__ in,
                                                         u16* __restrict__ out,
                                                         int R, int C) {
    __shared__ float T[32][33];
    const int tx = threadIdx.x & 31;
    const int ty = threadIdx.x >> 5;
    const int c0 = blockIdx.x * 32;
    const int r0 = blockIdx.y * 32;
#pragma unroll
    for (int p = 0; p < 4; ++p) {
        int ry = ty + p * 8;
        T[ry][tx] = in[(size_t)(r0 + ry) * C + c0 + tx];
    }
    __syncthreads();
#pragma unroll
    for (int p = 0; p < 4; ++p) {
        int cy = ty + p * 8;
        out[(size_t)(c0 + cy) * R + r0 + tx] = f2bf(T[tx][cy]);
    }
}

// ---------------------------------------------------------------------------
// GEMM1: qkv = x_bf16 @ w_qkv (via wqkvT), scatter Q(scaled)/K [bh][n][d],
// V transposed [bh][d][n].
// ---------------------------------------------------------------------------
__global__ __launch_bounds__(256) void gemm_qkv(const u16* __restrict__ A,
                                                const u16* __restrict__ BT,
                                                u16* __restrict__ Qb,
                                                u16* __restrict__ Kb,
                                                u16* __restrict__ Vt) {
    __shared__ u16 As[128][40];
    __shared__ u16 Bs[128][40];
    const int tid = threadIdx.x;
    const int lane = tid & 63;
    const int w = tid >> 6;
    const int wm = w >> 1, wn = w & 1;
    const int lr = lane & 15;
    const int lk = lane >> 4;
    const int row0 = blockIdx.y * 128;
    const int col0 = blockIdx.x * 128;

    f32x4 acc[4][4];
#pragma unroll
    for (int mi = 0; mi < 4; ++mi)
#pragma unroll
        for (int nj = 0; nj < 4; ++nj) acc[mi][nj] = (f32x4){0.f, 0.f, 0.f, 0.f};

    for (int k0 = 0; k0 < 768; k0 += 32) {
#pragma unroll
        for (int l = 0; l < 2; ++l) {
            int idx = tid + l * 256;
            int r = idx >> 2;
            int cg = idx & 3;
            *reinterpret_cast<int4*>(&As[r][cg * 8]) =
                *reinterpret_cast<const int4*>(&A[(size_t)(row0 + r) * 768 + k0 + cg * 8]);
            *reinterpret_cast<int4*>(&Bs[r][cg * 8]) =
                *reinterpret_cast<const int4*>(&BT[(size_t)(col0 + r) * 768 + k0 + cg * 8]);
        }
        __syncthreads();
        bf16x8 af[4], bfr[4];
#pragma unroll
        for (int mi = 0; mi < 4; ++mi)
            af[mi] = *reinterpret_cast<const bf16x8*>(&As[wm * 64 + mi * 16 + lr][lk * 8]);
#pragma unroll
        for (int nj = 0; nj < 4; ++nj)
            bfr[nj] = *reinterpret_cast<const bf16x8*>(&Bs[wn * 64 + nj * 16 + lr][lk * 8]);
#pragma unroll
        for (int mi = 0; mi < 4; ++mi)
#pragma unroll
            for (int nj = 0; nj < 4; ++nj)
                acc[mi][nj] = __builtin_amdgcn_mfma_f32_16x16x32_bf16(af[mi], bfr[nj], acc[mi][nj], 0, 0, 0);
        __syncthreads();
    }

    const int which = col0 / 768;
    const int cb = col0 - which * 768;
#pragma unroll
    for (int mi = 0; mi < 4; ++mi) {
#pragma unroll
        for (int i = 0; i < 4; ++i) {
            int r = row0 + wm * 64 + mi * 16 + lk * 4 + i;
            int b = r >> 10, n = r & 1023;
#pragma unroll
            for (int nj = 0; nj < 4; ++nj) {
                int cw = cb + wn * 64 + nj * 16 + lr;
                int h = cw >> 6, d = cw & 63;
                int bh = b * 12 + h;
                float val = acc[mi][nj][i];
                if (which == 0)      Qb[((size_t)bh * 1024 + n) * 64 + d] = f2bf(val * 0.18033688f); // 0.125*log2(e)
                else if (which == 1) Kb[((size_t)bh * 1024 + n) * 64 + d] = f2bf(val);
                else                 Vt[((size_t)bh * 64 + d) * 1024 + n] = f2bf(val);
            }
        }
    }
}

// ---------------------------------------------------------------------------
// Flash attention, swapped-operand 32x32x16 MFMA, no LDS in the KV loop.
// Block = 4 waves: wave w -> qsub = w&1 (32 q-rows), half = w>>1 (KV parity).
// Lane l handles q-row (l&31); S^T regs: key=(r&3)+8*(r>>2)+4*(l>>5).
// ---------------------------------------------------------------------------
#define GETO(dt, r) ((dt) == 0 ? o0[r] : o1[r])

__global__ __launch_bounds__(256) void attn_mfma(const u16* __restrict__ Qb,
                                                 const u16* __restrict__ Kb,
                                                 const u16* __restrict__ Vt,
                                                 u16* __restrict__ attn_out) {
    __shared__ float OtM[2][64][33];   // [qsub][d][q] partner O^T
    __shared__ float Lm[2][32], Ll[2][32];
    __shared__ u16 Os[2][32][72];      // [qsub][q][d] merged bf16

    const int tid = threadIdx.x;
    const int lane = tid & 63;
    const int w = tid >> 6;
    const int qsub = w & 1;
    const int half = w >> 1;
    const int l31 = lane & 31;
    const int hi = lane >> 5;

    // XCD swizzle: 96 consecutive remapped ids per XCD -> 6 bh per XCD L2
    const int bid = blockIdx.x;
    const int lin = (bid & 7) * 96 + (bid >> 3);
    const int qt = lin & 15;
    const int bh = lin >> 4;

    const u16* Qh = Qb + (size_t)bh * 65536;
    const u16* Kh = Kb + (size_t)bh * 65536;
    const u16* Vh = Vt + (size_t)bh * 65536;
    const int q0 = qt * 64 + qsub * 32;

    // Q fragments (B-operand): lane: col=q0+l31, k = kt*16 + hi*8 + j
    const u16* qbase = Qh + (size_t)(q0 + l31) * 64 + hi * 8;
    bf16x8 qf[4];
#pragma unroll
    for (int kt = 0; kt < 4; ++kt)
        qf[kt] = *reinterpret_cast<const bf16x8*>(qbase + kt * 16);

    f32x16 o0 = ZERO16, o1 = ZERO16;   // O^T: rows d (dt*32 + rowfml), col q=l31
    float m = -1e30f, l = 0.f;

    for (int it = 0; it < 8; ++it) {
        const int kv = (it * 2 + half) * 64;

        // K fragments (A-operand): row=key, k=d
        const u16* kbase = Kh + (size_t)(kv + l31) * 64 + hi * 8;
        bf16x8 kf0[4], kf1[4];
#pragma unroll
        for (int kt = 0; kt < 4; ++kt) {
            kf0[kt] = *reinterpret_cast<const bf16x8*>(kbase + kt * 16);
            kf1[kt] = *reinterpret_cast<const bf16x8*>(kbase + 32 * 64 + kt * 16);
        }
        // V fragments (A-operand of PV): row=d, k=key
        const u16* vbase = Vh + (size_t)l31 * 1024 + kv + hi * 8;
        bf16x8 vf0[4], vf1[4];
#pragma unroll
        for (int ks = 0; ks < 4; ++ks) {
            vf0[ks] = *reinterpret_cast<const bf16x8*>(vbase + ks * 16);
            vf1[ks] = *reinterpret_cast<const bf16x8*>(vbase + 32 * 1024 + ks * 16);
        }

        // S^T = K Q (pre-scaled, exp2 domain)
        f32x16 s0 = ZERO16, s1 = ZERO16;
#pragma unroll
        for (int kt = 0; kt < 4; ++kt) s0 = __builtin_amdgcn_mfma_f32_32x32x16_bf16(kf0[kt], qf[kt], s0, 0, 0, 0);
#pragma unroll
        for (int kt = 0; kt < 4; ++kt) s1 = __builtin_amdgcn_mfma_f32_32x32x16_bf16(kf1[kt], qf[kt], s1, 0, 0, 0);

        // tile max (in-lane tree + one cross-half exchange)
        float mx[8];
#pragma unroll
        for (int i = 0; i < 8; ++i)
            mx[i] = fmaxf(fmaxf(s0[2*i], s0[2*i+1]), fmaxf(s1[2*i], s1[2*i+1]));
        float pmax = fmaxf(fmaxf(fmaxf(mx[0], mx[1]), fmaxf(mx[2], mx[3])),
                           fmaxf(fmaxf(mx[4], mx[5]), fmaxf(mx[6], mx[7])));
        pmax = xhalf_max(pmax);

        // defer-max rescale (T13, THR=8 in log2 units)
        if (!__all(pmax <= m + 8.f)) {
            float mn = fmaxf(m, pmax);
            float c = __builtin_amdgcn_exp2f(m - mn);
            m = mn; l *= c;
            o0 = o0 * c; o1 = o1 * c;
        }

        // P = exp2(S - m)
#pragma unroll
        for (int r = 0; r < 16; ++r) s0[r] = __builtin_amdgcn_exp2f(s0[r] - m);
#pragma unroll
        for (int r = 0; r < 16; ++r) s1[r] = __builtin_amdgcn_exp2f(s1[r] - m);
        float sm[8];
#pragma unroll
        for (int i = 0; i < 8; ++i)
            sm[i] = (s0[2*i] + s0[2*i+1]) + (s1[2*i] + s1[2*i+1]);
        float tsum = ((sm[0]+sm[1]) + (sm[2]+sm[3])) + ((sm[4]+sm[5]) + (sm[6]+sm[7]));
        l += xhalf_sum(tsum);

        // pack P -> bf16 B-fragments.  Fragment word layout (per 16-key MFMA ks):
        //   word j2 holds keys {hi*8 + j2*2, +1} of this lane's q column.
        // Cross-half exchange via shfl_xor(32).
        bf16x8 pb[4];
#define PACK_GROUP(S, G, OUT)                                           \
        {                                                               \
            u32 X0 = cvtpk(S[8*(G)+0], S[8*(G)+1]);                     \
            u32 X1 = cvtpk(S[8*(G)+2], S[8*(G)+3]);                     \
            u32 Y0 = cvtpk(S[8*(G)+4], S[8*(G)+5]);                     \
            u32 Y1 = cvtpk(S[8*(G)+6], S[8*(G)+7]);                     \
            u32 X0s = (u32)__shfl_xor((int)X0, 32);                     \
            u32 X1s = (u32)__shfl_xor((int)X1, 32);                     \
            u32 Y0s = (u32)__shfl_xor((int)Y0, 32);                     \
            u32 Y1s = (u32)__shfl_xor((int)Y1, 32);                     \
            union { u32 u[4]; bf16x8 v; } pk_;                          \
            pk_.u[0] = hi ? Y0s : X0;                                   \
            pk_.u[1] = hi ? Y1s : X1;                                   \
            pk_.u[2] = hi ? Y0 : X0s;                                   \
            pk_.u[3] = hi ? Y1 : X1s;                                   \
            OUT = pk_.v;                                                \
        }
        PACK_GROUP(s0, 0, pb[0]);
        PACK_GROUP(s0, 1, pb[1]);
        PACK_GROUP(s1, 0, pb[2]);
        PACK_GROUP(s1, 1, pb[3]);
#undef PACK_GROUP

        // O^T += V^T P
#pragma unroll
        for (int ks = 0; ks < 4; ++ks) {
            o0 = __builtin_amdgcn_mfma_f32_32x32x16_bf16(vf0[ks], pb[ks], o0, 0, 0, 0);
            o1 = __builtin_amdgcn_mfma_f32_32x32x16_bf16(vf1[ks], pb[ks], o1, 0, 0, 0);
        }
    }

    // merge the two KV-parity halves via LDS
    if (half == 1) {
#pragma unroll
        for (int dt = 0; dt < 2; ++dt)
#pragma unroll
            for (int r = 0; r < 16; ++r)
                OtM[qsub][dt * 32 + (r & 3) + 8 * (r >> 2) + 4 * hi][l31] = GETO(dt, r);
        Lm[qsub][l31] = m;
        Ll[qsub][l31] = l;
    }
    __syncthreads();
    if (half == 0) {
        float m2 = Lm[qsub][l31], l2 = Ll[qsub][l31];
        float mn = fmaxf(m, m2);
        float a = __builtin_amdgcn_exp2f(m - mn);
        float bsc = __builtin_amdgcn_exp2f(m2 - mn);
        float lm = l * a + l2 * bsc;
        float inv = 1.0f / lm;
        float av = a * inv, bv = bsc * inv;
#pragma unroll
        for (int dt = 0; dt < 2; ++dt)
#pragma unroll
            for (int rq = 0; rq < 4; ++rq) {
                int d0 = dt * 32 + 8 * rq + 4 * hi;
                float v0 = GETO(dt, rq * 4 + 0) * av + OtM[qsub][d0 + 0][l31] * bv;
                float v1 = GETO(dt, rq * 4 + 1) * av + OtM[qsub][d0 + 1][l31] * bv;
                float v2 = GETO(dt, rq * 4 + 2) * av + OtM[qsub][d0 + 2][l31] * bv;
                float v3 = GETO(dt, rq * 4 + 3) * av + OtM[qsub][d0 + 3][l31] * bv;
                uint2 pr;
                pr.x = cvtpk(v0, v1);
                pr.y = cvtpk(v2, v3);
                *reinterpret_cast<uint2*>(&Os[qsub][l31][d0]) = pr;
            }
    }
    __syncthreads();

    // coalesced write-out: 64 tokens x 64 d
    const int b = bh / 12, h = bh % 12;
#pragma unroll
    for (int it2 = 0; it2 < 2; ++it2) {
        int idx = tid + it2 * 256;       // 0..511
        int token = idx >> 3;            // 0..63
        int chunk = idx & 7;
        int4 v = *reinterpret_cast<const int4*>(&Os[token >> 5][token & 31][chunk * 8]);
        *reinterpret_cast<int4*>(&attn_out[((size_t)(b * 1024 + qt * 64 + token)) * 768 + h * 64 + chunk * 8]) = v;
    }
}

// ---------------------------------------------------------------------------
// GEMM2: out = attn_bf16 @ w_out (via woutT) + b_out.
// ---------------------------------------------------------------------------
__global__ __launch_bounds__(256) void gemm_out(const u16* __restrict__ A,
                                                const u16* __restrict__ BT,
                                                const float* __restrict__ bias,
                                                float* __restrict__ out) {
    __shared__ u16 As[128][40];
    __shared__ u16 Bs[128][40];
    const int tid = threadIdx.x;
    const int lane = tid & 63;
    const int w = tid >> 6;
    const int wm = w >> 1, wn = w & 1;
    const int lr = lane & 15;
    const int lk = lane >> 4;
    const int row0 = blockIdx.y * 128;
    const int col0 = blockIdx.x * 128;

    f32x4 acc[4][4];
#pragma unroll
    for (int mi = 0; mi < 4; ++mi)
#pragma unroll
        for (int nj = 0; nj < 4; ++nj) acc[mi][nj] = (f32x4){0.f, 0.f, 0.f, 0.f};

    for (int k0 = 0; k0 < 768; k0 += 32) {
#pragma unroll
        for (int l = 0; l < 2; ++l) {
            int idx = tid + l * 256;
            int r = idx >> 2;
            int cg = idx & 3;
            *reinterpret_cast<int4*>(&As[r][cg * 8]) =
                *reinterpret_cast<const int4*>(&A[(size_t)(row0 + r) * 768 + k0 + cg * 8]);
            *reinterpret_cast<int4*>(&Bs[r][cg * 8]) =
                *reinterpret_cast<const int4*>(&BT[(size_t)(col0 + r) * 768 + k0 + cg * 8]);
        }
        __syncthreads();
        bf16x8 af[4], bfr[4];
#pragma unroll
        for (int mi = 0; mi < 4; ++mi)
            af[mi] = *reinterpret_cast<const bf16x8*>(&As[wm * 64 + mi * 16 + lr][lk * 8]);
#pragma unroll
        for (int nj = 0; nj < 4; ++nj)
            bfr[nj] = *reinterpret_cast<const bf16x8*>(&Bs[wn * 64 + nj * 16 + lr][lk * 8]);
#pragma unroll
        for (int mi = 0; mi < 4; ++mi)
#pragma unroll
            for (int nj = 0; nj < 4; ++nj)
                acc[mi][nj] = __builtin_amdgcn_mfma_f32_16x16x32_bf16(af[mi], bfr[nj], acc[mi][nj], 0, 0, 0);
        __syncthreads();
    }

#pragma unroll
    for (int mi = 0; mi < 4; ++mi)
#pragma unroll
        for (int i = 0; i < 4; ++i) {
            int r = row0 + wm * 64 + mi * 16 + lk * 4 + i;
#pragma unroll
            for (int nj = 0; nj < 4; ++nj) {
                int c = col0 + wn * 64 + nj * 16 + lr;
                out[(size_t)r * 768 + c] = acc[mi][nj][i] + bias[c];
            }
        }
}

// ---------------------------------------------------------------------------
extern "C" void kernel_launch(void* const* d_in, const int* in_sizes, int n_in,
                              void* d_out, int out_size, void* d_ws, size_t ws_size,
                              hipStream_t stream) {
    const float* x     = (const float*)d_in[0];
    const float* w_qkv = (const float*)d_in[1];
    const float* w_out = (const float*)d_in[2];
    const float* b_out = (const float*)d_in[3];
    float* out = (float*)d_out;

    u16* ws = (u16*)d_ws;
    const size_t n_x = (size_t)4096 * 768;
    u16* xb     = ws;
    u16* wqkvT  = xb + n_x;
    u16* woutT  = wqkvT + (size_t)2304 * 768;
    u16* Qb     = woutT + (size_t)768 * 768;
    u16* Kb     = Qb + n_x;
    u16* Vtr    = Kb + n_x;                       // [48][64][1024]
    u16* attnb  = Vtr + n_x;

    convert_x<<<(786432 + 255) / 256, 256, 0, stream>>>(x, xb, 786432);
    transpose_convert<<<dim3(72, 24), 256, 0, stream>>>(w_qkv, wqkvT, 768, 2304);
    transpose_convert<<<dim3(24, 24), 256, 0, stream>>>(w_out, woutT, 768, 768);
    gemm_qkv<<<dim3(18, 32), 256, 0, stream>>>(xb, wqkvT, Qb, Kb, Vtr);
    attn_mfma<<<768, 256, 0, stream>>>(Qb, Kb, Vtr, attnb);
    gemm_out<<<dim3(6, 32), 256, 0, stream>>>(attnb, woutT, b_out, out);
}